// Round 20
// baseline (368.072 us; speedup 1.0000x reference)
//
#include <hip/hip_runtime.h>
#include <hip/hip_bf16.h>
#include <math.h>

constexpr int B_ = 4;
constexpr int F_ = 32;
constexpr int H_ = 320;
constexpr int W_ = 320;
constexpr int HW_ = H_ * W_;
constexpr int NS_ = 25;

typedef short short8 __attribute__((ext_vector_type(8)));
typedef short short4v __attribute__((ext_vector_type(4)));
typedef float f32x4 __attribute__((ext_vector_type(4)));
typedef __bf16 bf16x8 __attribute__((ext_vector_type(8)));

__device__ __forceinline__ float lrelu(float x) { return x >= 0.f ? x : 0.2f * x; }

__device__ __forceinline__ short bf16_of(float f) {
  __hip_bfloat16 h = __float2bfloat16(f);
  return __builtin_bit_cast(short, h);
}
__device__ __forceinline__ float f_of_bf16(short s) {
  unsigned int u = ((unsigned int)(unsigned short)s) << 16;
  return __builtin_bit_cast(float, u);
}

__device__ __forceinline__ void mfma16(f32x4& acc, short8 a, short8 b) {
  acc = __builtin_amdgcn_mfma_f32_16x16x32_bf16(
      __builtin_bit_cast(bf16x8, a), __builtin_bit_cast(bf16x8, b), acc, 0, 0, 0);
}

// ---------------- q/k: 1x1 conv (32->8) + L2 norm ----------------
__global__ __launch_bounds__(256) void qk_kernel(
    const float* __restrict__ x, const float* __restrict__ wq,
    const float* __restrict__ wk, float* __restrict__ qg, float* __restrict__ kg,
    __hip_bfloat16* __restrict__ qb3, __hip_bfloat16* __restrict__ kb2)
{
  __shared__ float swq[256], swk[256];
  int tid = threadIdx.x;
  swq[tid] = wq[tid];
  swk[tid] = wk[tid];
  __syncthreads();
  int idx = blockIdx.x * 256 + tid;
  int b = idx / HW_, p = idx % HW_;
  const float* xp = x + (size_t)b * F_ * HW_ + p;
  float xv[32];
#pragma unroll
  for (int c = 0; c < 32; ++c) xv[c] = xp[(size_t)c * HW_];
  float qv[8], kv[8];
#pragma unroll
  for (int f = 0; f < 8; ++f) {
    float aq = 0.f, ak = 0.f;
#pragma unroll
    for (int c = 0; c < 32; ++c) {
      aq += swq[f * 32 + c] * xv[c];
      ak += swk[f * 32 + c] * xv[c];
    }
    qv[f] = aq; kv[f] = ak;
  }
  float nq = 0.f, nk = 0.f;
#pragma unroll
  for (int f = 0; f < 8; ++f) { nq += qv[f] * qv[f]; nk += kv[f] * kv[f]; }
  nq = 1.f / (sqrtf(nq) + 1e-6f);
  nk = 1.f / (sqrtf(nk) + 1e-6f);
  int y = p / W_, xx = p % W_;
  size_t off3 = (((size_t)b * 326 + (y + 3)) * 326 + (xx + 3)) * 8;
  size_t off2 = (((size_t)b * 324 + (y + 2)) * 324 + (xx + 2)) * 8;
  float4 q0 = {qv[0] * nq, qv[1] * nq, qv[2] * nq, qv[3] * nq};
  float4 q1 = {qv[4] * nq, qv[5] * nq, qv[6] * nq, qv[7] * nq};
  float4 k0 = {kv[0] * nk, kv[1] * nk, kv[2] * nk, kv[3] * nk};
  float4 k1 = {kv[4] * nk, kv[5] * nk, kv[6] * nk, kv[7] * nk};
  *(float4*)(qg + off3) = q0; *(float4*)(qg + off3 + 4) = q1;
  *(float4*)(kg + off3) = k0; *(float4*)(kg + off3 + 4) = k1;
  short8 qh, kh;
#pragma unroll
  for (int f = 0; f < 4; ++f) { qh[f] = bf16_of(((float*)&q0)[f]); kh[f] = bf16_of(((float*)&k0)[f]); }
#pragma unroll
  for (int f = 0; f < 4; ++f) { qh[4 + f] = bf16_of(((float*)&q1)[f]); kh[4 + f] = bf16_of(((float*)&k1)[f]); }
  *(short8*)(qb3 + off3) = qh;
  *(short8*)(kb2 + off2) = kh;
}

// ---------------- dot: 25 shifted q·k + smoothing -> 32-ch bf16 NHWC (halo-2) ----------------
__global__ __launch_bounds__(256) void dot_kernel(
    const float* __restrict__ qg, const float* __restrict__ kg,
    __hip_bfloat16* __restrict__ dotb)
{
  int idx = blockIdx.x * 256 + threadIdx.x;
  int b = idx / HW_, p = idx % HW_;
  int y = p / W_, x = p % W_;
  size_t off3 = (((size_t)b * 326 + (y + 3)) * 326 + (x + 3)) * 8;
  float4 k0 = *(const float4*)(kg + off3), k1 = *(const float4*)(kg + off3 + 4);
  float raw[25];
  float mx = -1e30f;
#pragma unroll
  for (int si = -2; si <= 2; ++si) {
#pragma unroll
    for (int sj = -2; sj <= 2; ++sj) {
      int s = (si + 2) * 5 + (sj + 2);
      const float* qp = qg + off3 + ((size_t)(-si) * 326 - sj) * 8;
      float4 q0 = *(const float4*)qp, q1 = *(const float4*)(qp + 4);
      float acc = q0.x * k0.x + q0.y * k0.y + q0.z * k0.z + q0.w * k0.w
                + q1.x * k1.x + q1.y * k1.y + q1.z * k1.z + q1.w * k1.w;
      raw[s] = 1.f - acc;
      mx = fmaxf(mx, raw[s]);
    }
  }
  float inv = 4.f / (mx + 1e-6f);
  __hip_bfloat16* dst = dotb + (((size_t)b * 324 + (y + 2)) * 324 + (x + 2)) * 32;
#pragma unroll
  for (int f0 = 0; f0 < 32; f0 += 8) {
    short8 o;
#pragma unroll
    for (int j = 0; j < 8; ++j) {
      int s = f0 + j;
      o[j] = (s < 25) ? bf16_of(1.f - raw[s] * inv) : (short)0;
    }
    *(short8*)(dst + f0) = o;
  }
}

// ---------------- wfuse: fused front weights -> bf16, FRAGMENT-ORDERED ----------------
__global__ __launch_bounds__(256) void wfuse_kernel(
    const float* __restrict__ wd, const float* __restrict__ wnl, short* __restrict__ wfb)
{
  int e = blockIdx.x * 256 + threadIdx.x;
  if (e >= 25600) return;
  int j = e & 7;
  int co = (e >> 3) & 31;
  int gq = e >> 8;
  int g = gq >> 2, qq = gq & 3;
  int k = g * 32 + qq * 8 + j;
  float v = 0.f;
  if (k < 416) {
    int tt = k >> 3, c = k & 7;
    if (tt < 49) {
      int dy = tt / 7 - 3, dx = tt % 7 - 3;
#pragma unroll
      for (int ty = 0; ty < 3; ++ty)
#pragma unroll
        for (int tx = 0; tx < 3; ++tx) {
          int si = ty - 1 - dy, sj = tx - 1 - dx;
          if (si >= -2 && si <= 2 && sj >= -2 && sj <= 2) {
            int s = (si + 2) * 5 + (sj + 2);
            v += wnl[co * 25 + s] * wd[(s * 9 + c) * 9 + ty * 3 + tx];
          }
        }
    }
  } else if (k < 512) {
    int kk = k - 416;
    int tt = kk >> 3, c = kk & 7;
    if (tt < 9) {
      float sum = 0.f;
      for (int s = 0; s < 25; ++s) sum += wnl[co * 25 + s] * wd[(s * 9 + c) * 9 + tt];
      v = -sum;
    }
  } else {
    int kk = k - 512;
    int tt = kk >> 5, c = kk & 31;
    if (c < 25) v = wnl[co * 25 + c] * wd[(c * 9 + 8) * 9 + tt];
  }
  wfb[e] = bf16_of(v);
}

// ---------------- wprep: all mconv weights -> bf16 frag-ordered ----------------
__global__ __launch_bounds__(256) void wprep_kernel(
    const float* __restrict__ wh, const float* __restrict__ wd1, const float* __restrict__ wd2,
    const float* __restrict__ we0, const float* __restrict__ wu2, const float* __restrict__ wu1,
    short* __restrict__ out)
{
  int z = blockIdx.z;
  const float* wt; int CIN, KSS, base;
  switch (z) {
    case 0: wt = wh;  CIN = 32; KSS = 9;  base = 0;     break;
    case 1: wt = wd1; CIN = 32; KSS = 16; base = 9216;  break;
    case 2: wt = wd2; CIN = 32; KSS = 16; base = 25600; break;
    case 3: wt = we0; CIN = 32; KSS = 9;  base = 41984; break;
    case 4: wt = wu2; CIN = 32; KSS = 9;  base = 51200; break;
    default: wt = wu1; CIN = 64; KSS = 9; base = 60416; break;
  }
  int n = 32 * KSS * CIN;
  int e = blockIdx.x * 256 + threadIdx.x;
  if (e >= n) return;
  int j = e & 7;
  int co = (e >> 3) & 31;
  int gq = e >> 8;
  int g = gq >> 2, qs = gq & 3;
  int k = g * 32 + qs * 8 + j;
  int t = k / CIN, ci = k % CIN;
  out[base + e] = bf16_of(wt[((size_t)co * CIN + ci) * KSS + t]);
}

// ---------------- fconv (NO LDS, NPW=2, prefetch): per g: 2 A + 2 B loads + 4 MFMAs ----------------
// grid (10,80,4) = 3200 blocks -> 12800 waves (max TLP).
__global__ __launch_bounds__(256) void fconv_kernel(
    const __hip_bfloat16* __restrict__ qb3, const __hip_bfloat16* __restrict__ kb2,
    const __hip_bfloat16* __restrict__ dotb, const short* __restrict__ wfb,
    __hip_bfloat16* __restrict__ yb)
{
  int tid = threadIdx.x;
  int wid = tid >> 6, lane = tid & 63;
  int p = lane & 15, q = lane >> 4;
  int b = blockIdx.z;
  int oy = blockIdx.y * 4 + wid;
  int ox0 = blockIdx.x * 32;

  const short* wA = wfb + ((q * 32) + p) * 8;

  const char* qRow = (const char*)qb3 + (((size_t)b * 326 + (oy + 3)) * 326 + (ox0 + 3 + p)) * 16;
  const char* kRow = (const char*)kb2 + (((size_t)b * 324 + (oy + 2)) * 324 + (ox0 + 2 + p)) * 16;
  const char* dRow = (const char*)dotb + (((size_t)b * 324 + (oy + 2)) * 324 + (ox0 + 2 + p)) * 64 + q * 16;

  int offQ[13];
#pragma unroll
  for (int g = 0; g < 13; ++g) {
    int tt = 4 * g + q; if (tt > 48) tt = 48;
    offQ[g] = ((tt / 7 - 3) * 326 + (tt % 7 - 3)) * 16;
  }
  int offK[3];
#pragma unroll
  for (int g = 0; g < 3; ++g) {
    int tt = 4 * g + q; if (tt > 8) tt = 8;
    offK[g] = ((tt / 3 - 1) * 324 + (tt % 3 - 1)) * 16;
  }

  auto baseOf = [&](int g, const char*& base, int& pst) {
    if (g < 13) { base = qRow + offQ[g]; pst = 256; }
    else if (g < 16) { base = kRow + offK[g - 13]; pst = 256; }
    else {
      int tt = g - 16;
      base = dRow + ((tt / 3 - 1) * 324 + (tt % 3 - 1)) * 64;
      pst = 1024;
    }
  };

  f32x4 acc[2][2];
#pragma unroll
  for (int s = 0; s < 2; ++s)
#pragma unroll
    for (int h = 0; h < 2; ++h) acc[s][h] = (f32x4){0.f, 0.f, 0.f, 0.f};

  short8 a0c, a1c, b0c, b1c;
  {
    const char* base; int pst;
    baseOf(0, base, pst);
    a0c = *(const short8*)(wA);
    a1c = *(const short8*)(wA + 128);
    b0c = *(const short8*)(base);
    b1c = *(const short8*)(base + pst);
  }

#pragma unroll
  for (int g = 0; g < 25; ++g) {
    short8 a0n, a1n, b0n, b1n;
    if (g < 24) {
      const char* base; int pst;
      baseOf(g + 1, base, pst);
      a0n = *(const short8*)(wA + (g + 1) * 1024);
      a1n = *(const short8*)(wA + (g + 1) * 1024 + 128);
      b0n = *(const short8*)(base);
      b1n = *(const short8*)(base + pst);
    }
    mfma16(acc[0][0], a0c, b0c); mfma16(acc[0][1], a1c, b0c);
    mfma16(acc[1][0], a0c, b1c); mfma16(acc[1][1], a1c, b1c);
    if (g < 24) {
      a0c = a0n; a1c = a1n;
      b0c = b0n; b1c = b1n;
    }
  }

#pragma unroll
  for (int s = 0; s < 2; ++s) {
    int ox = ox0 + s * 16 + p;
    bool ring = (oy == 0) || (oy == 319) || (ox == 0) || (ox == 319);
    __hip_bfloat16* dst = yb + (((size_t)b * 324 + (oy + 2)) * 324 + (ox + 2)) * 32;
    short4v w0, w1;
#pragma unroll
    for (int rr = 0; rr < 4; ++rr) {
      float v0 = acc[s][0][rr], v1 = acc[s][1][rr];
      if (!ring) { v0 = lrelu(v0); v1 = lrelu(v1); }
      w0[rr] = bf16_of(v0); w1[rr] = bf16_of(v1);
    }
    *(short4v*)(dst + q * 4) = w0;
    *(short4v*)(dst + 16 + q * 4) = w1;
  }
}

// ---------------- fixup: boundary-ring correction + lrelu ----------------
__global__ __launch_bounds__(256) void fixup_kernel(
    const __hip_bfloat16* __restrict__ qb3, const float* __restrict__ wd,
    const float* __restrict__ wnl, __hip_bfloat16* __restrict__ yb)
{
  int idx = blockIdx.x * 256 + threadIdx.x;
  int b = blockIdx.y;
  if (idx >= 1276) return;
  int y, x;
  if (idx < 320) { y = 0; x = idx; }
  else if (idx < 640) { y = 319; x = idx - 320; }
  else if (idx < 958) { y = idx - 640 + 1; x = 0; }
  else { y = idx - 958 + 1; x = 319; }
  float ep[32];
#pragma unroll
  for (int f = 0; f < 32; ++f) ep[f] = 0.f;
  for (int s = 0; s < 25; ++s) {
    int si = s / 5 - 2, sj = s % 5 - 2;
    float es = 0.f;
#pragma unroll
    for (int ty = 0; ty < 3; ++ty)
#pragma unroll
      for (int tx = 0; tx < 3; ++tx) {
        int py = y + ty - 1, px = x + tx - 1;
        if ((unsigned)py < 320u && (unsigned)px < 320u) continue;
        int qy = py - si + 3, qx = px - sj + 3;
        const __hip_bfloat16* qp = qb3 + (((size_t)b * 326 + qy) * 326 + qx) * 8;
        short8 qv = *(const short8*)qp;
        float t = 0.f;
#pragma unroll
        for (int c = 0; c < 8; ++c) t += wd[(s * 9 + c) * 9 + ty * 3 + tx] * f_of_bf16(qv[c]);
        es += t;
      }
#pragma unroll
    for (int f = 0; f < 32; ++f) ep[f] += wnl[f * 25 + s] * es;
  }
  __hip_bfloat16* dst = yb + (((size_t)b * 324 + (y + 2)) * 324 + (x + 2)) * 32;
#pragma unroll
  for (int f0 = 0; f0 < 32; f0 += 8) {
    short8 v = *(short8*)(dst + f0);
    short8 o;
#pragma unroll
    for (int j = 0; j < 8; ++j) o[j] = bf16_of(lrelu(f_of_bf16(v[j]) - ep[f0 + j]));
    *(short8*)(dst + f0) = o;
  }
}

// ---------------- rim zeroing for q/k padded buffers ----------------
__global__ void rim4_kernel(float* qg, float* kg, __hip_bfloat16* qb3, __hip_bfloat16* kb2) {
  int idx = blockIdx.x * 256 + threadIdx.x;
  int b = blockIdx.y;
  char* buf; int P, hw, n16;
  switch (blockIdx.z) {
    case 0: buf = (char*)qg;  P = 326; hw = 3; n16 = 2; break;
    case 1: buf = (char*)kg;  P = 326; hw = 3; n16 = 2; break;
    case 2: buf = (char*)qb3; P = 326; hw = 3; n16 = 1; break;
    default: buf = (char*)kb2; P = 324; hw = 2; n16 = 1; break;
  }
  int tw = 2 * hw;
  int nt = tw * P + (P - tw) * tw;
  if (idx >= nt) return;
  int y, x;
  if (idx < hw * P) { y = idx / P; x = idx % P; }
  else if (idx < tw * P) { int r = idx - hw * P; y = P - hw + r / P; x = r % P; }
  else { int r = idx - tw * P; int row = r / tw, c = r % tw; y = hw + row; x = (c < hw) ? c : (P - tw + c); }
  size_t off = ((size_t)b * P * P + (size_t)y * P + x) * (size_t)(n16 * 16);
  int4 z = {0, 0, 0, 0};
  int4* ptr = (int4*)(buf + off);
  ptr[0] = z;
  if (n16 == 2) ptr[1] = z;
}

// ---------------- batched halo zeroing ----------------
__device__ __forceinline__ void halo_body(__hip_bfloat16* buf, int H, int W, int idx, int b) {
  int Wp = W + 4, Hp = H + 4;
  int nt = 4 * Wp + 4 * H;
  if (idx >= nt) return;
  int y, x;
  if (idx < 2 * Wp) { y = idx / Wp; x = idx % Wp; }
  else if (idx < 4 * Wp) { int r = idx - 2 * Wp; y = Hp - 2 + r / Wp; x = r % Wp; }
  else { int r = idx - 4 * Wp; int row = r >> 2; int c = r & 3; y = 2 + row; x = (c < 2) ? c : (Wp - 4 + c); }
  int4* p = (int4*)(buf + ((size_t)b * Hp * Wp + (size_t)y * Wp + x) * 32);
  int4 z = {0, 0, 0, 0};
  p[0] = z; p[1] = z; p[2] = z; p[3] = z;
}

__global__ void halo_zero3(__hip_bfloat16* b0, __hip_bfloat16* b1, __hip_bfloat16* b2) {
  int idx = blockIdx.x * 256 + threadIdx.x;
  __hip_bfloat16* buf = (blockIdx.z == 0) ? b0 : (blockIdx.z == 1) ? b1 : b2;
  halo_body(buf, 320, 320, idx, blockIdx.y);
}

__global__ void halo_zero5(__hip_bfloat16* d1, __hip_bfloat16* u2, __hip_bfloat16* d2,
                           __hip_bfloat16* e0, __hip_bfloat16* u1) {
  int idx = blockIdx.x * 256 + threadIdx.x;
  __hip_bfloat16* buf; int H;
  switch (blockIdx.z) {
    case 0: buf = d1; H = 160; break;
    case 1: buf = u2; H = 160; break;
    case 2: buf = d2; H = 80; break;
    case 3: buf = e0; H = 80; break;
    default: buf = u1; H = 320; break;
  }
  halo_body(buf, H, H, idx, blockIdx.y);
}

// ---------------- MFMA implicit-GEMM conv, NO LDS, SW-pipelined prefetch ----------------
template <int CIN, int KS, int STRIDE, bool UP, bool TWO, int NPW, int NROW>
__global__ __launch_bounds__(256) void mconv(
    const __hip_bfloat16* __restrict__ in1, const __hip_bfloat16* __restrict__ in2,
    const short* __restrict__ wb,
    __hip_bfloat16* __restrict__ outb,
    float2* __restrict__ partials,
    int Hin, int Win, int Hout, int Wout)
{
  constexpr int KSS = KS * KS;
  constexpr int K = KSS * CIN;
  constexpr int NG = K / 32;
  int tid = threadIdx.x;
  int wid = tid >> 6, lane = tid & 63;
  int p = lane & 15, q = lane >> 4;
  int b = blockIdx.z;
  int oyg = blockIdx.y * 4 + wid;
  int oy0 = oyg * NROW;
  int ox0 = blockIdx.x * (16 * NPW);

  const short* wA = wb + ((q * 32) + p) * 8;

  int RS = (Win + 4) * 64;
  size_t IMG = (size_t)(Hin + 4) * RS;
  const char* base1 = (const char*)in1 + (size_t)b * IMG;
  const char* base2 = TWO ? ((const char*)in2 + (size_t)b * IMG) : nullptr;

  int colB[NPW][KS];
#pragma unroll
  for (int s = 0; s < NPW; ++s)
#pragma unroll
    for (int dx = 0; dx < KS; ++dx) {
      int ox = ox0 + s * 16 + p;
      int ix = ox * STRIDE - 1 + dx;
      int sx = UP ? (ix >> 1) : ix;
      colB[s][dx] = (sx + 2) * 64 + q * 16;
    }
  int rowOff[NROW][KS];
#pragma unroll
  for (int r = 0; r < NROW; ++r)
#pragma unroll
    for (int dy = 0; dy < KS; ++dy) {
      int iy = (oy0 + r) * STRIDE - 1 + dy;
      int sy = UP ? (iy >> 1) : iy;
      rowOff[r][dy] = (sy + 2) * RS;
    }

  auto loadB = [&](int g, short8 bf[NROW][NPW]) {
    int t = TWO ? (g >> 1) : g;
    int dy = t / KS, dx = t % KS;
    const char* src = (TWO && (g & 1)) ? base2 : base1;
#pragma unroll
    for (int r = 0; r < NROW; ++r)
#pragma unroll
      for (int s = 0; s < NPW; ++s)
        bf[r][s] = *(const short8*)(src + rowOff[r][dy] + colB[s][dx]);
  };

  f32x4 acc[NROW][NPW][2];
#pragma unroll
  for (int r = 0; r < NROW; ++r)
#pragma unroll
    for (int s = 0; s < NPW; ++s)
#pragma unroll
      for (int h = 0; h < 2; ++h) acc[r][s][h] = (f32x4){0.f, 0.f, 0.f, 0.f};

  short8 a0c, a1c;
  short8 bc[NROW][NPW];
  a0c = *(const short8*)(wA);
  a1c = *(const short8*)(wA + 128);
  loadB(0, bc);

#pragma unroll
  for (int g = 0; g < NG; ++g) {
    short8 a0n, a1n;
    short8 bn[NROW][NPW];
    if (g < NG - 1) {
      a0n = *(const short8*)(wA + (g + 1) * 1024);
      a1n = *(const short8*)(wA + (g + 1) * 1024 + 128);
      loadB(g + 1, bn);
    }
#pragma unroll
    for (int r = 0; r < NROW; ++r)
#pragma unroll
      for (int s = 0; s < NPW; ++s) {
        mfma16(acc[r][s][0], a0c, bc[r][s]);
        mfma16(acc[r][s][1], a1c, bc[r][s]);
      }
    if (g < NG - 1) {
      a0c = a0n; a1c = a1n;
#pragma unroll
      for (int r = 0; r < NROW; ++r)
#pragma unroll
        for (int s = 0; s < NPW; ++s) bc[r][s] = bn[r][s];
    }
  }

  int RSO = (Wout + 4) * 64;
#pragma unroll
  for (int r = 0; r < NROW; ++r) {
    char* ob = (char*)outb + (size_t)b * (Hout + 4) * RSO + (size_t)(oy0 + r + 2) * RSO;
#pragma unroll
    for (int s = 0; s < NPW; ++s) {
      char* pxp = ob + (size_t)(ox0 + s * 16 + p + 2) * 64;
#pragma unroll
      for (int h = 0; h < 2; ++h) {
        short4v w4;
#pragma unroll
        for (int rr = 0; rr < 4; ++rr) w4[rr] = bf16_of(acc[r][s][h][rr]);
        *(short4v*)(pxp + h * 32 + q * 8) = w4;
      }
    }
  }
  float sv[2][4], qv[2][4];
#pragma unroll
  for (int h = 0; h < 2; ++h)
#pragma unroll
    for (int rr = 0; rr < 4; ++rr) {
      float ts = 0.f, tq = 0.f;
#pragma unroll
      for (int r = 0; r < NROW; ++r)
#pragma unroll
        for (int s = 0; s < NPW; ++s) { float v = acc[r][s][h][rr]; ts += v; tq += v * v; }
      sv[h][rr] = ts; qv[h][rr] = tq;
    }
#pragma unroll
  for (int off = 1; off <= 8; off <<= 1)
#pragma unroll
    for (int h = 0; h < 2; ++h)
#pragma unroll
      for (int rr = 0; rr < 4; ++rr) {
        sv[h][rr] += __shfl_xor(sv[h][rr], off);
        qv[h][rr] += __shfl_xor(qv[h][rr], off);
      }
  if (p == 0) {
    int nbx = gridDim.x;
    int NT = (Hout / NROW) * nbx;
    int tile = oyg * nbx + blockIdx.x;
#pragma unroll
    for (int h = 0; h < 2; ++h)
#pragma unroll
      for (int rr = 0; rr < 4; ++rr) {
        int co = h * 16 + q * 4 + rr;
        partials[(size_t)(b * 32 + co) * NT + tile] = make_float2(sv[h][rr], qv[h][rr]);
      }
  }
}

// ---------------- tail2: 3x3 conv 64->1, channel-split wave layout ----------------
__global__ __launch_bounds__(256) void tail2_kernel(
    const __hip_bfloat16* __restrict__ d0b, const __hip_bfloat16* __restrict__ u1b,
    const float* __restrict__ wt, float* __restrict__ out)
{
  __shared__ float wsh[576];
  int tid = threadIdx.x;
  for (int e = tid; e < 576; e += 256) wsh[e] = wt[e];
  __syncthreads();
  int wid = tid >> 6, lane = tid & 63;
  int p = lane & 15, q = lane >> 4;
  int b = blockIdx.z;
  int oy = blockIdx.y * 4 + wid;
  int ox = blockIdx.x * 16 + p;
  const __hip_bfloat16* src = (q < 2) ? d0b : u1b;
  int cb = (q & 1) * 16;
  const float* wb = &wsh[((q >> 1) * 32 + cb) * 9];
  const short8* px0 = (const short8*)(src + (((size_t)b * 324 + (oy + 1)) * 324 + (ox + 1)) * 32 + cb);
  float accA = 0.f, accB = 0.f;
#pragma unroll
  for (int dy = 0; dy < 3; ++dy)
#pragma unroll
    for (int dx = 0; dx < 3; ++dx) {
      int tap = dy * 3 + dx;
      const short8* ptr = px0 + ((size_t)dy * 324 + dx) * 4;
      short8 v0 = ptr[0], v1 = ptr[1];
#pragma unroll
      for (int j = 0; j < 8; ++j) {
        accA = fmaf(wb[j * 9 + tap], f_of_bf16(v0[j]), accA);
        accB = fmaf(wb[(8 + j) * 9 + tap], f_of_bf16(v1[j]), accB);
      }
    }
  float acc = accA + accB;
  acc += __shfl_xor(acc, 16);
  acc += __shfl_xor(acc, 32);
  if (q == 0) out[((size_t)b * H_ + oy) * W_ + ox] = acc;
}

// ---------------- stats: reduce tile partials -> mean, rstd ----------------
__global__ __launch_bounds__(256) void stats_kernel(
    const float2* __restrict__ partials, float2* __restrict__ mv, int NT, int N)
{
  int bc = blockIdx.x;
  int tid = threadIdx.x;
  float s = 0.f, sq = 0.f;
  for (int t = tid; t < NT; t += 256) {
    float2 v = partials[(size_t)bc * NT + t];
    s += v.x; sq += v.y;
  }
#pragma unroll
  for (int off = 32; off >= 1; off >>= 1) {
    s += __shfl_xor(s, off);
    sq += __shfl_xor(sq, off);
  }
  __shared__ float rs[4], rq[4];
  int wid = tid >> 6;
  if ((tid & 63) == 0) { rs[wid] = s; rq[wid] = sq; }
  __syncthreads();
  if (tid == 0) {
    s = rs[0] + rs[1] + rs[2] + rs[3];
    sq = rq[0] + rq[1] + rq[2] + rq[3];
    float mean = s / (float)N;
    float var = sq / (float)N - mean * mean;
    mv[bc] = make_float2(mean, rsqrtf(fmaxf(var, 0.f) + 1e-5f));
  }
}

// ---------------- in-place instance-norm + lrelu on padded NHWC bf16 ----------------
__global__ __launch_bounds__(256) void bnorm_kernel(
    __hip_bfloat16* __restrict__ buf, const float2* __restrict__ mv, int H, int W)
{
  int idx = blockIdx.x * 256 + threadIdx.x;
  int total = B_ * H * W * 4;
  if (idx >= total) return;
  int g = idx & 3;
  int px = idx >> 2;
  int x = px % W; int t = px / W; int y = t % H; int b = t / H;
  int Wp = W + 4;
  size_t off = ((size_t)b * (H + 4) * Wp + (size_t)(y + 2) * Wp + (x + 2)) * 32 + g * 8;
  short8* ptr = (short8*)(buf + off);
  short8 v = *ptr;
  const float2* m = mv + b * 32 + g * 8;
  short8 o;
#pragma unroll
  for (int j = 0; j < 8; ++j) {
    float2 p2 = m[j];
    float f = f_of_bf16(v[j]);
    f = lrelu((f - p2.x) * p2.y);
    o[j] = bf16_of(f);
  }
  *ptr = o;
}

extern "C" void kernel_launch(void* const* d_in, const int* in_sizes, int n_in,
                              void* d_out, int out_size, void* d_ws, size_t ws_size,
                              hipStream_t stream) {
  (void)in_sizes; (void)n_in; (void)out_size; (void)ws_size;
  const float* x       = (const float*)d_in[0];
  const float* w_q     = (const float*)d_in[1];
  const float* w_k     = (const float*)d_in[2];
  const float* w_direct= (const float*)d_in[3];
  const float* w_nl    = (const float*)d_in[4];
  const float* w_head  = (const float*)d_in[5];
  const float* w_down1 = (const float*)d_in[6];
  const float* w_down2 = (const float*)d_in[7];
  const float* w_e0    = (const float*)d_in[8];
  const float* w_up2   = (const float*)d_in[9];
  const float* w_up1   = (const float*)d_in[10];
  const float* w_tail  = (const float*)d_in[11];
  float* out = (float*)d_out;

  // ---- workspace layout (bytes), liveness-aliased ----
  char* ws = (char*)d_ws;
  float* qg = (float*)(ws + 0);
  float* kg = (float*)(ws + 13603328);
  __hip_bfloat16* qb3  = (__hip_bfloat16*)(ws + 27206656);
  __hip_bfloat16* kb2  = (__hip_bfloat16*)(ws + 34008320);
  __hip_bfloat16* dotb = (__hip_bfloat16*)(ws + 40726784);
  __hip_bfloat16* u1b  = dotb;
  __hip_bfloat16* yb   = (__hip_bfloat16*)(ws + 67600640);
  __hip_bfloat16* d0b  = (__hip_bfloat16*)(ws + 94474496);
  short* wfb           = (short*)(ws + 121348352);
  short* wmc           = (short*)(ws + 121399552);
  float2* partials     = (float2*)(ws + 121557248);
  float2* mv           = (float2*)(ws + 124834048);
  __hip_bfloat16* d1b  = (__hip_bfloat16*)(ws + 0);
  __hip_bfloat16* d2b  = (__hip_bfloat16*)(ws + 6885376);
  __hip_bfloat16* e0b  = (__hip_bfloat16*)(ws + 8691712);
  __hip_bfloat16* u2b  = (__hip_bfloat16*)(ws + 13603328);

  short* w_headb = wmc + 0;
  short* w_d1b   = wmc + 9216;
  short* w_d2b   = wmc + 25600;
  short* w_e0b   = wmc + 41984;
  short* w_u2b   = wmc + 51200;
  short* w_u1b   = wmc + 60416;

  rim4_kernel<<<dim3(16, 4, 4), 256, 0, stream>>>(qg, kg, qb3, kb2);
  halo_zero3<<<dim3(11, 4, 3), 256, 0, stream>>>(yb, d0b, dotb);
  wprep_kernel<<<dim3(72, 1, 6), 256, 0, stream>>>(
      w_head, w_down1, w_down2, w_e0, w_up2, w_up1, wmc);

  qk_kernel<<<1600, 256, 0, stream>>>(x, w_q, w_k, qg, kg, qb3, kb2);
  dot_kernel<<<1600, 256, 0, stream>>>(qg, kg, dotb);
  wfuse_kernel<<<100, 256, 0, stream>>>(w_direct, w_nl, wfb);

  // fused front conv: no-LDS, NPW=2 (3200 blocks, max TLP)
  fconv_kernel<<<dim3(10, 80, 4), 256, 0, stream>>>(qb3, kb2, dotb, wfb, yb);
  fixup_kernel<<<dim3(5, 4), 256, 0, stream>>>(qb3, w_direct, w_nl, yb);

  halo_zero5<<<dim3(11, 4, 5), 256, 0, stream>>>(d1b, u2b, d2b, e0b, u1b);

  // ---- bf16 MFMA conv stack ----
  mconv<32, 3, 1, false, false, 2, 1><<<dim3(10, 80, 4), 256, 0, stream>>>(
      yb, nullptr, w_headb, d0b, partials, 320, 320, 320, 320);
  stats_kernel<<<128, 256, 0, stream>>>(partials, mv, 3200, 102400);
  bnorm_kernel<<<6400, 256, 0, stream>>>(d0b, mv, 320, 320);

  mconv<32, 4, 2, false, false, 2, 1><<<dim3(5, 40, 4), 256, 0, stream>>>(
      d0b, nullptr, w_d1b, d1b, partials, 320, 320, 160, 160);
  stats_kernel<<<128, 256, 0, stream>>>(partials, mv, 800, 25600);
  bnorm_kernel<<<1600, 256, 0, stream>>>(d1b, mv, 160, 160);

  mconv<32, 4, 2, false, false, 1, 1><<<dim3(5, 20, 4), 256, 0, stream>>>(
      d1b, nullptr, w_d2b, d2b, partials, 160, 160, 80, 80);
  stats_kernel<<<128, 256, 0, stream>>>(partials, mv, 400, 6400);
  bnorm_kernel<<<400, 256, 0, stream>>>(d2b, mv, 80, 80);

  mconv<32, 3, 1, false, false, 1, 1><<<dim3(5, 20, 4), 256, 0, stream>>>(
      d2b, nullptr, w_e0b, e0b, partials, 80, 80, 80, 80);
  stats_kernel<<<128, 256, 0, stream>>>(partials, mv, 400, 6400);
  bnorm_kernel<<<400, 256, 0, stream>>>(e0b, mv, 80, 80);

  mconv<32, 3, 1, true, false, 2, 1><<<dim3(5, 40, 4), 256, 0, stream>>>(
      e0b, nullptr, w_u2b, u2b, partials, 80, 80, 160, 160);
  stats_kernel<<<128, 256, 0, stream>>>(partials, mv, 800, 25600);
  bnorm_kernel<<<1600, 256, 0, stream>>>(u2b, mv, 160, 160);

  mconv<64, 3, 1, true, true, 2, 1><<<dim3(10, 80, 4), 256, 0, stream>>>(
      d1b, u2b, w_u1b, u1b, partials, 160, 160, 320, 320);
  stats_kernel<<<128, 256, 0, stream>>>(partials, mv, 3200, 102400);
  bnorm_kernel<<<6400, 256, 0, stream>>>(u1b, mv, 320, 320);

  tail2_kernel<<<dim3(20, 80, 4), 256, 0, stream>>>(d0b, u1b, w_tail, out);
}

// Round 21
// 358.658 us; speedup vs baseline: 1.0262x; 1.0262x over previous
//
#include <hip/hip_runtime.h>
#include <hip/hip_bf16.h>
#include <math.h>

constexpr int B_ = 4;
constexpr int F_ = 32;
constexpr int H_ = 320;
constexpr int W_ = 320;
constexpr int HW_ = H_ * W_;
constexpr int NS_ = 25;

typedef short short8 __attribute__((ext_vector_type(8)));
typedef short short4v __attribute__((ext_vector_type(4)));
typedef float f32x4 __attribute__((ext_vector_type(4)));
typedef __bf16 bf16x8 __attribute__((ext_vector_type(8)));

__device__ __forceinline__ float lrelu(float x) { return x >= 0.f ? x : 0.2f * x; }

__device__ __forceinline__ short bf16_of(float f) {
  __hip_bfloat16 h = __float2bfloat16(f);
  return __builtin_bit_cast(short, h);
}
__device__ __forceinline__ float f_of_bf16(short s) {
  unsigned int u = ((unsigned int)(unsigned short)s) << 16;
  return __builtin_bit_cast(float, u);
}

__device__ __forceinline__ void mfma16(f32x4& acc, short8 a, short8 b) {
  acc = __builtin_amdgcn_mfma_f32_16x16x32_bf16(
      __builtin_bit_cast(bf16x8, a), __builtin_bit_cast(bf16x8, b), acc, 0, 0, 0);
}

// ---------------- q/k: 1x1 conv (32->8) + L2 norm ----------------
__global__ __launch_bounds__(256) void qk_kernel(
    const float* __restrict__ x, const float* __restrict__ wq,
    const float* __restrict__ wk, float* __restrict__ qg, float* __restrict__ kg,
    __hip_bfloat16* __restrict__ qb3, __hip_bfloat16* __restrict__ kb2)
{
  __shared__ float swq[256], swk[256];
  int tid = threadIdx.x;
  swq[tid] = wq[tid];
  swk[tid] = wk[tid];
  __syncthreads();
  int idx = blockIdx.x * 256 + tid;
  int b = idx / HW_, p = idx % HW_;
  const float* xp = x + (size_t)b * F_ * HW_ + p;
  float xv[32];
#pragma unroll
  for (int c = 0; c < 32; ++c) xv[c] = xp[(size_t)c * HW_];
  float qv[8], kv[8];
#pragma unroll
  for (int f = 0; f < 8; ++f) {
    float aq = 0.f, ak = 0.f;
#pragma unroll
    for (int c = 0; c < 32; ++c) {
      aq += swq[f * 32 + c] * xv[c];
      ak += swk[f * 32 + c] * xv[c];
    }
    qv[f] = aq; kv[f] = ak;
  }
  float nq = 0.f, nk = 0.f;
#pragma unroll
  for (int f = 0; f < 8; ++f) { nq += qv[f] * qv[f]; nk += kv[f] * kv[f]; }
  nq = 1.f / (sqrtf(nq) + 1e-6f);
  nk = 1.f / (sqrtf(nk) + 1e-6f);
  int y = p / W_, xx = p % W_;
  size_t off3 = (((size_t)b * 326 + (y + 3)) * 326 + (xx + 3)) * 8;
  size_t off2 = (((size_t)b * 324 + (y + 2)) * 324 + (xx + 2)) * 8;
  float4 q0 = {qv[0] * nq, qv[1] * nq, qv[2] * nq, qv[3] * nq};
  float4 q1 = {qv[4] * nq, qv[5] * nq, qv[6] * nq, qv[7] * nq};
  float4 k0 = {kv[0] * nk, kv[1] * nk, kv[2] * nk, kv[3] * nk};
  float4 k1 = {kv[4] * nk, kv[5] * nk, kv[6] * nk, kv[7] * nk};
  *(float4*)(qg + off3) = q0; *(float4*)(qg + off3 + 4) = q1;
  *(float4*)(kg + off3) = k0; *(float4*)(kg + off3 + 4) = k1;
  short8 qh, kh;
#pragma unroll
  for (int f = 0; f < 4; ++f) { qh[f] = bf16_of(((float*)&q0)[f]); kh[f] = bf16_of(((float*)&k0)[f]); }
#pragma unroll
  for (int f = 0; f < 4; ++f) { qh[4 + f] = bf16_of(((float*)&q1)[f]); kh[4 + f] = bf16_of(((float*)&k1)[f]); }
  *(short8*)(qb3 + off3) = qh;
  *(short8*)(kb2 + off2) = kh;
}

// ---------------- dot: 25 shifted q·k + smoothing -> 32-ch bf16 NHWC (halo-2) ----------------
__global__ __launch_bounds__(256) void dot_kernel(
    const float* __restrict__ qg, const float* __restrict__ kg,
    __hip_bfloat16* __restrict__ dotb)
{
  int idx = blockIdx.x * 256 + threadIdx.x;
  int b = idx / HW_, p = idx % HW_;
  int y = p / W_, x = p % W_;
  size_t off3 = (((size_t)b * 326 + (y + 3)) * 326 + (x + 3)) * 8;
  float4 k0 = *(const float4*)(kg + off3), k1 = *(const float4*)(kg + off3 + 4);
  float raw[25];
  float mx = -1e30f;
#pragma unroll
  for (int si = -2; si <= 2; ++si) {
#pragma unroll
    for (int sj = -2; sj <= 2; ++sj) {
      int s = (si + 2) * 5 + (sj + 2);
      const float* qp = qg + off3 + ((size_t)(-si) * 326 - sj) * 8;
      float4 q0 = *(const float4*)qp, q1 = *(const float4*)(qp + 4);
      float acc = q0.x * k0.x + q0.y * k0.y + q0.z * k0.z + q0.w * k0.w
                + q1.x * k1.x + q1.y * k1.y + q1.z * k1.z + q1.w * k1.w;
      raw[s] = 1.f - acc;
      mx = fmaxf(mx, raw[s]);
    }
  }
  float inv = 4.f / (mx + 1e-6f);
  __hip_bfloat16* dst = dotb + (((size_t)b * 324 + (y + 2)) * 324 + (x + 2)) * 32;
#pragma unroll
  for (int f0 = 0; f0 < 32; f0 += 8) {
    short8 o;
#pragma unroll
    for (int j = 0; j < 8; ++j) {
      int s = f0 + j;
      o[j] = (s < 25) ? bf16_of(1.f - raw[s] * inv) : (short)0;
    }
    *(short8*)(dst + f0) = o;
  }
}

// ---------------- wfuse: fused front weights -> bf16, FRAGMENT-ORDERED ----------------
__global__ __launch_bounds__(256) void wfuse_kernel(
    const float* __restrict__ wd, const float* __restrict__ wnl, short* __restrict__ wfb)
{
  int e = blockIdx.x * 256 + threadIdx.x;
  if (e >= 25600) return;
  int j = e & 7;
  int co = (e >> 3) & 31;
  int gq = e >> 8;
  int g = gq >> 2, qq = gq & 3;
  int k = g * 32 + qq * 8 + j;
  float v = 0.f;
  if (k < 416) {
    int tt = k >> 3, c = k & 7;
    if (tt < 49) {
      int dy = tt / 7 - 3, dx = tt % 7 - 3;
#pragma unroll
      for (int ty = 0; ty < 3; ++ty)
#pragma unroll
        for (int tx = 0; tx < 3; ++tx) {
          int si = ty - 1 - dy, sj = tx - 1 - dx;
          if (si >= -2 && si <= 2 && sj >= -2 && sj <= 2) {
            int s = (si + 2) * 5 + (sj + 2);
            v += wnl[co * 25 + s] * wd[(s * 9 + c) * 9 + ty * 3 + tx];
          }
        }
    }
  } else if (k < 512) {
    int kk = k - 416;
    int tt = kk >> 3, c = kk & 7;
    if (tt < 9) {
      float sum = 0.f;
      for (int s = 0; s < 25; ++s) sum += wnl[co * 25 + s] * wd[(s * 9 + c) * 9 + tt];
      v = -sum;
    }
  } else {
    int kk = k - 512;
    int tt = kk >> 5, c = kk & 31;
    if (c < 25) v = wnl[co * 25 + c] * wd[(c * 9 + 8) * 9 + tt];
  }
  wfb[e] = bf16_of(v);
}

// ---------------- wprep: all mconv weights -> bf16 frag-ordered ----------------
__global__ __launch_bounds__(256) void wprep_kernel(
    const float* __restrict__ wh, const float* __restrict__ wd1, const float* __restrict__ wd2,
    const float* __restrict__ we0, const float* __restrict__ wu2, const float* __restrict__ wu1,
    short* __restrict__ out)
{
  int z = blockIdx.z;
  const float* wt; int CIN, KSS, base;
  switch (z) {
    case 0: wt = wh;  CIN = 32; KSS = 9;  base = 0;     break;
    case 1: wt = wd1; CIN = 32; KSS = 16; base = 9216;  break;
    case 2: wt = wd2; CIN = 32; KSS = 16; base = 25600; break;
    case 3: wt = we0; CIN = 32; KSS = 9;  base = 41984; break;
    case 4: wt = wu2; CIN = 32; KSS = 9;  base = 51200; break;
    default: wt = wu1; CIN = 64; KSS = 9; base = 60416; break;
  }
  int n = 32 * KSS * CIN;
  int e = blockIdx.x * 256 + threadIdx.x;
  if (e >= n) return;
  int j = e & 7;
  int co = (e >> 3) & 31;
  int gq = e >> 8;
  int g = gq >> 2, qs = gq & 3;
  int k = g * 32 + qs * 8 + j;
  int t = k / CIN, ci = k % CIN;
  out[base + e] = bf16_of(wt[((size_t)co * CIN + ci) * KSS + t]);
}

// ---------------- fconv (NO LDS, A from global, NROW=1) ----------------
__global__ __launch_bounds__(256) void fconv_kernel(
    const __hip_bfloat16* __restrict__ qb3, const __hip_bfloat16* __restrict__ kb2,
    const __hip_bfloat16* __restrict__ dotb, const short* __restrict__ wfb,
    __hip_bfloat16* __restrict__ yb)
{
  int tid = threadIdx.x;
  int wid = tid >> 6, lane = tid & 63;
  int p = lane & 15, q = lane >> 4;
  int b = blockIdx.z;
  int oy = blockIdx.y * 4 + wid;
  int ox0 = blockIdx.x * 64;

  const short* wA = wfb + ((q * 32) + p) * 8;

  const char* qRow = (const char*)qb3 + (((size_t)b * 326 + (oy + 3)) * 326 + (ox0 + 3 + p)) * 16;
  const char* kRow = (const char*)kb2 + (((size_t)b * 324 + (oy + 2)) * 324 + (ox0 + 2 + p)) * 16;
  const char* dRow = (const char*)dotb + (((size_t)b * 324 + (oy + 2)) * 324 + (ox0 + 2 + p)) * 64 + q * 16;

  int offQ[13];
#pragma unroll
  for (int g = 0; g < 13; ++g) {
    int tt = 4 * g + q; if (tt > 48) tt = 48;
    offQ[g] = ((tt / 7 - 3) * 326 + (tt % 7 - 3)) * 16;
  }
  int offK[3];
#pragma unroll
  for (int g = 0; g < 3; ++g) {
    int tt = 4 * g + q; if (tt > 8) tt = 8;
    offK[g] = ((tt / 3 - 1) * 324 + (tt % 3 - 1)) * 16;
  }

  f32x4 acc[4][2];
#pragma unroll
  for (int s = 0; s < 4; ++s)
#pragma unroll
    for (int h = 0; h < 2; ++h) acc[s][h] = (f32x4){0.f, 0.f, 0.f, 0.f};

#pragma unroll
  for (int g = 0; g < 25; ++g) {
    short8 a0 = *(const short8*)(wA + g * 1024);
    short8 a1 = *(const short8*)(wA + g * 1024 + 128);
    const char* base;
    int pst;
    if (g < 13) { base = qRow + offQ[g]; pst = 256; }
    else if (g < 16) { base = kRow + offK[g - 13]; pst = 256; }
    else {
      int tt = g - 16;
      base = dRow + ((tt / 3 - 1) * 324 + (tt % 3 - 1)) * 64;
      pst = 1024;
    }
    short8 b0 = *(const short8*)(base);
    short8 b1 = *(const short8*)(base + pst);
    short8 b2 = *(const short8*)(base + 2 * pst);
    short8 b3 = *(const short8*)(base + 3 * pst);
    mfma16(acc[0][0], a0, b0); mfma16(acc[0][1], a1, b0);
    mfma16(acc[1][0], a0, b1); mfma16(acc[1][1], a1, b1);
    mfma16(acc[2][0], a0, b2); mfma16(acc[2][1], a1, b2);
    mfma16(acc[3][0], a0, b3); mfma16(acc[3][1], a1, b3);
  }

#pragma unroll
  for (int s = 0; s < 4; ++s) {
    int ox = ox0 + s * 16 + p;
    bool ring = (oy == 0) || (oy == 319) || (ox == 0) || (ox == 319);
    __hip_bfloat16* dst = yb + (((size_t)b * 324 + (oy + 2)) * 324 + (ox + 2)) * 32;
    short4v w0, w1;
#pragma unroll
    for (int rr = 0; rr < 4; ++rr) {
      float v0 = acc[s][0][rr], v1 = acc[s][1][rr];
      if (!ring) { v0 = lrelu(v0); v1 = lrelu(v1); }
      w0[rr] = bf16_of(v0); w1[rr] = bf16_of(v1);
    }
    *(short4v*)(dst + q * 4) = w0;
    *(short4v*)(dst + 16 + q * 4) = w1;
  }
}

// ---------------- fixup: boundary-ring correction of the Q-term pad mask + lrelu ----------------
__global__ __launch_bounds__(256) void fixup_kernel(
    const __hip_bfloat16* __restrict__ qb3, const float* __restrict__ wd,
    const float* __restrict__ wnl, __hip_bfloat16* __restrict__ yb)
{
  int idx = blockIdx.x * 256 + threadIdx.x;
  int b = blockIdx.y;
  if (idx >= 1276) return;
  int y, x;
  if (idx < 320) { y = 0; x = idx; }
  else if (idx < 640) { y = 319; x = idx - 320; }
  else if (idx < 958) { y = idx - 640 + 1; x = 0; }
  else { y = idx - 958 + 1; x = 319; }
  float ep[32];
#pragma unroll
  for (int f = 0; f < 32; ++f) ep[f] = 0.f;
  for (int s = 0; s < 25; ++s) {
    int si = s / 5 - 2, sj = s % 5 - 2;
    float es = 0.f;
#pragma unroll
    for (int ty = 0; ty < 3; ++ty)
#pragma unroll
      for (int tx = 0; tx < 3; ++tx) {
        int py = y + ty - 1, px = x + tx - 1;
        if ((unsigned)py < 320u && (unsigned)px < 320u) continue;
        int qy = py - si + 3, qx = px - sj + 3;
        const __hip_bfloat16* qp = qb3 + (((size_t)b * 326 + qy) * 326 + qx) * 8;
        short8 qv = *(const short8*)qp;
        float t = 0.f;
#pragma unroll
        for (int c = 0; c < 8; ++c) t += wd[(s * 9 + c) * 9 + ty * 3 + tx] * f_of_bf16(qv[c]);
        es += t;
      }
#pragma unroll
    for (int f = 0; f < 32; ++f) ep[f] += wnl[f * 25 + s] * es;
  }
  __hip_bfloat16* dst = yb + (((size_t)b * 324 + (y + 2)) * 324 + (x + 2)) * 32;
#pragma unroll
  for (int f0 = 0; f0 < 32; f0 += 8) {
    short8 v = *(short8*)(dst + f0);
    short8 o;
#pragma unroll
    for (int j = 0; j < 8; ++j) o[j] = bf16_of(lrelu(f_of_bf16(v[j]) - ep[f0 + j]));
    *(short8*)(dst + f0) = o;
  }
}

// ---------------- rim zeroing for q/k padded buffers ----------------
__global__ void rim4_kernel(float* qg, float* kg, __hip_bfloat16* qb3, __hip_bfloat16* kb2) {
  int idx = blockIdx.x * 256 + threadIdx.x;
  int b = blockIdx.y;
  char* buf; int P, hw, n16;
  switch (blockIdx.z) {
    case 0: buf = (char*)qg;  P = 326; hw = 3; n16 = 2; break;
    case 1: buf = (char*)kg;  P = 326; hw = 3; n16 = 2; break;
    case 2: buf = (char*)qb3; P = 326; hw = 3; n16 = 1; break;
    default: buf = (char*)kb2; P = 324; hw = 2; n16 = 1; break;
  }
  int tw = 2 * hw;
  int nt = tw * P + (P - tw) * tw;
  if (idx >= nt) return;
  int y, x;
  if (idx < hw * P) { y = idx / P; x = idx % P; }
  else if (idx < tw * P) { int r = idx - hw * P; y = P - hw + r / P; x = r % P; }
  else { int r = idx - tw * P; int row = r / tw, c = r % tw; y = hw + row; x = (c < hw) ? c : (P - tw + c); }
  size_t off = ((size_t)b * P * P + (size_t)y * P + x) * (size_t)(n16 * 16);
  int4 z = {0, 0, 0, 0};
  int4* ptr = (int4*)(buf + off);
  ptr[0] = z;
  if (n16 == 2) ptr[1] = z;
}

// ---------------- batched halo zeroing ----------------
__device__ __forceinline__ void halo_body(__hip_bfloat16* buf, int H, int W, int idx, int b) {
  int Wp = W + 4, Hp = H + 4;
  int nt = 4 * Wp + 4 * H;
  if (idx >= nt) return;
  int y, x;
  if (idx < 2 * Wp) { y = idx / Wp; x = idx % Wp; }
  else if (idx < 4 * Wp) { int r = idx - 2 * Wp; y = Hp - 2 + r / Wp; x = r % Wp; }
  else { int r = idx - 4 * Wp; int row = r >> 2; int c = r & 3; y = 2 + row; x = (c < 2) ? c : (Wp - 4 + c); }
  int4* p = (int4*)(buf + ((size_t)b * Hp * Wp + (size_t)y * Wp + x) * 32);
  int4 z = {0, 0, 0, 0};
  p[0] = z; p[1] = z; p[2] = z; p[3] = z;
}

__global__ void halo_zero3(__hip_bfloat16* b0, __hip_bfloat16* b1, __hip_bfloat16* b2) {
  int idx = blockIdx.x * 256 + threadIdx.x;
  __hip_bfloat16* buf = (blockIdx.z == 0) ? b0 : (blockIdx.z == 1) ? b1 : b2;
  halo_body(buf, 320, 320, idx, blockIdx.y);
}

__global__ void halo_zero5(__hip_bfloat16* d1, __hip_bfloat16* u2, __hip_bfloat16* d2,
                           __hip_bfloat16* e0, __hip_bfloat16* u1) {
  int idx = blockIdx.x * 256 + threadIdx.x;
  __hip_bfloat16* buf; int H;
  switch (blockIdx.z) {
    case 0: buf = d1; H = 160; break;
    case 1: buf = u2; H = 160; break;
    case 2: buf = d2; H = 80; break;
    case 3: buf = e0; H = 80; break;
    default: buf = u1; H = 320; break;
  }
  halo_body(buf, H, H, idx, blockIdx.y);
}

// ---------------- MFMA implicit-GEMM conv, NO LDS (A frag-ordered from global) ----------------
template <int CIN, int KS, int STRIDE, bool UP, bool TWO, int NPW, int NROW>
__global__ __launch_bounds__(256) void mconv(
    const __hip_bfloat16* __restrict__ in1, const __hip_bfloat16* __restrict__ in2,
    const short* __restrict__ wb,
    __hip_bfloat16* __restrict__ outb,
    float2* __restrict__ partials,
    int Hin, int Win, int Hout, int Wout)
{
  constexpr int KSS = KS * KS;
  constexpr int K = KSS * CIN;
  constexpr int NG = K / 32;
  int tid = threadIdx.x;
  int wid = tid >> 6, lane = tid & 63;
  int p = lane & 15, q = lane >> 4;
  int b = blockIdx.z;
  int oyg = blockIdx.y * 4 + wid;
  int oy0 = oyg * NROW;
  int ox0 = blockIdx.x * (16 * NPW);

  const short* wA = wb + ((q * 32) + p) * 8;   // + g*1024 per group

  int RS = (Win + 4) * 64;
  size_t IMG = (size_t)(Hin + 4) * RS;
  const char* base1 = (const char*)in1 + (size_t)b * IMG;
  const char* base2 = TWO ? ((const char*)in2 + (size_t)b * IMG) : nullptr;

  int colB[NPW][KS];
#pragma unroll
  for (int s = 0; s < NPW; ++s)
#pragma unroll
    for (int dx = 0; dx < KS; ++dx) {
      int ox = ox0 + s * 16 + p;
      int ix = ox * STRIDE - 1 + dx;
      int sx = UP ? (ix >> 1) : ix;
      colB[s][dx] = (sx + 2) * 64 + q * 16;
    }
  int rowOff[NROW][KS];
#pragma unroll
  for (int r = 0; r < NROW; ++r)
#pragma unroll
    for (int dy = 0; dy < KS; ++dy) {
      int iy = (oy0 + r) * STRIDE - 1 + dy;
      int sy = UP ? (iy >> 1) : iy;
      rowOff[r][dy] = (sy + 2) * RS;
    }

  f32x4 acc[NROW][NPW][2];
#pragma unroll
  for (int r = 0; r < NROW; ++r)
#pragma unroll
    for (int s = 0; s < NPW; ++s)
#pragma unroll
      for (int h = 0; h < 2; ++h) acc[r][s][h] = (f32x4){0.f, 0.f, 0.f, 0.f};

#pragma unroll
  for (int g = 0; g < NG; ++g) {
    int t = TWO ? (g >> 1) : g;
    int dy = t / KS, dx = t % KS;
    const char* src = (TWO && (g & 1)) ? base2 : base1;
    short8 a0 = *(const short8*)(wA + g * 1024);
    short8 a1 = *(const short8*)(wA + g * 1024 + 128);
    short8 bf[NROW][NPW];
#pragma unroll
    for (int r = 0; r < NROW; ++r)
#pragma unroll
      for (int s = 0; s < NPW; ++s)
        bf[r][s] = *(const short8*)(src + rowOff[r][dy] + colB[s][dx]);
#pragma unroll
    for (int r = 0; r < NROW; ++r)
#pragma unroll
      for (int s = 0; s < NPW; ++s) {
        mfma16(acc[r][s][0], a0, bf[r][s]);
        mfma16(acc[r][s][1], a1, bf[r][s]);
      }
  }

  int RSO = (Wout + 4) * 64;
#pragma unroll
  for (int r = 0; r < NROW; ++r) {
    char* ob = (char*)outb + (size_t)b * (Hout + 4) * RSO + (size_t)(oy0 + r + 2) * RSO;
#pragma unroll
    for (int s = 0; s < NPW; ++s) {
      char* pxp = ob + (size_t)(ox0 + s * 16 + p + 2) * 64;
#pragma unroll
      for (int h = 0; h < 2; ++h) {
        short4v w4;
#pragma unroll
        for (int rr = 0; rr < 4; ++rr) w4[rr] = bf16_of(acc[r][s][h][rr]);
        *(short4v*)(pxp + h * 32 + q * 8) = w4;
      }
    }
  }
  float sv[2][4], qv[2][4];
#pragma unroll
  for (int h = 0; h < 2; ++h)
#pragma unroll
    for (int rr = 0; rr < 4; ++rr) {
      float ts = 0.f, tq = 0.f;
#pragma unroll
      for (int r = 0; r < NROW; ++r)
#pragma unroll
        for (int s = 0; s < NPW; ++s) { float v = acc[r][s][h][rr]; ts += v; tq += v * v; }
      sv[h][rr] = ts; qv[h][rr] = tq;
    }
#pragma unroll
  for (int off = 1; off <= 8; off <<= 1)
#pragma unroll
    for (int h = 0; h < 2; ++h)
#pragma unroll
      for (int rr = 0; rr < 4; ++rr) {
        sv[h][rr] += __shfl_xor(sv[h][rr], off);
        qv[h][rr] += __shfl_xor(qv[h][rr], off);
      }
  if (p == 0) {
    int nbx = gridDim.x;
    int NT = (Hout / NROW) * nbx;
    int tile = oyg * nbx + blockIdx.x;
#pragma unroll
    for (int h = 0; h < 2; ++h)
#pragma unroll
      for (int rr = 0; rr < 4; ++rr) {
        int co = h * 16 + q * 4 + rr;
        partials[(size_t)(b * 32 + co) * NT + tile] = make_float2(sv[h][rr], qv[h][rr]);
      }
  }
}

// ---------------- tail2: 3x3 conv 64->1, channel-split wave layout ----------------
__global__ __launch_bounds__(256) void tail2_kernel(
    const __hip_bfloat16* __restrict__ d0b, const __hip_bfloat16* __restrict__ u1b,
    const float* __restrict__ wt, float* __restrict__ out)
{
  __shared__ float wsh[576];
  int tid = threadIdx.x;
  for (int e = tid; e < 576; e += 256) wsh[e] = wt[e];
  __syncthreads();
  int wid = tid >> 6, lane = tid & 63;
  int p = lane & 15, q = lane >> 4;
  int b = blockIdx.z;
  int oy = blockIdx.y * 4 + wid;
  int ox = blockIdx.x * 16 + p;
  const __hip_bfloat16* src = (q < 2) ? d0b : u1b;
  int cb = (q & 1) * 16;
  const float* wb = &wsh[((q >> 1) * 32 + cb) * 9];
  const short8* px0 = (const short8*)(src + (((size_t)b * 324 + (oy + 1)) * 324 + (ox + 1)) * 32 + cb);
  float accA = 0.f, accB = 0.f;
#pragma unroll
  for (int dy = 0; dy < 3; ++dy)
#pragma unroll
    for (int dx = 0; dx < 3; ++dx) {
      int tap = dy * 3 + dx;
      const short8* ptr = px0 + ((size_t)dy * 324 + dx) * 4;
      short8 v0 = ptr[0], v1 = ptr[1];
#pragma unroll
      for (int j = 0; j < 8; ++j) {
        accA = fmaf(wb[j * 9 + tap], f_of_bf16(v0[j]), accA);
        accB = fmaf(wb[(8 + j) * 9 + tap], f_of_bf16(v1[j]), accB);
      }
    }
  float acc = accA + accB;
  acc += __shfl_xor(acc, 16);
  acc += __shfl_xor(acc, 32);
  if (q == 0) out[((size_t)b * H_ + oy) * W_ + ox] = acc;
}

// ---------------- stats: reduce tile partials -> mean, rstd ----------------
__global__ __launch_bounds__(256) void stats_kernel(
    const float2* __restrict__ partials, float2* __restrict__ mv, int NT, int N)
{
  int bc = blockIdx.x;
  int tid = threadIdx.x;
  float s = 0.f, sq = 0.f;
  for (int t = tid; t < NT; t += 256) {
    float2 v = partials[(size_t)bc * NT + t];
    s += v.x; sq += v.y;
  }
#pragma unroll
  for (int off = 32; off >= 1; off >>= 1) {
    s += __shfl_xor(s, off);
    sq += __shfl_xor(sq, off);
  }
  __shared__ float rs[4], rq[4];
  int wid = tid >> 6;
  if ((tid & 63) == 0) { rs[wid] = s; rq[wid] = sq; }
  __syncthreads();
  if (tid == 0) {
    s = rs[0] + rs[1] + rs[2] + rs[3];
    sq = rq[0] + rq[1] + rq[2] + rq[3];
    float mean = s / (float)N;
    float var = sq / (float)N - mean * mean;
    mv[bc] = make_float2(mean, rsqrtf(fmaxf(var, 0.f) + 1e-5f));
  }
}

// ---------------- in-place instance-norm + lrelu on padded NHWC bf16 ----------------
__global__ __launch_bounds__(256) void bnorm_kernel(
    __hip_bfloat16* __restrict__ buf, const float2* __restrict__ mv, int H, int W)
{
  int idx = blockIdx.x * 256 + threadIdx.x;
  int total = B_ * H * W * 4;
  if (idx >= total) return;
  int g = idx & 3;
  int px = idx >> 2;
  int x = px % W; int t = px / W; int y = t % H; int b = t / H;
  int Wp = W + 4;
  size_t off = ((size_t)b * (H + 4) * Wp + (size_t)(y + 2) * Wp + (x + 2)) * 32 + g * 8;
  short8* ptr = (short8*)(buf + off);
  short8 v = *ptr;
  const float2* m = mv + b * 32 + g * 8;
  short8 o;
#pragma unroll
  for (int j = 0; j < 8; ++j) {
    float2 p2 = m[j];
    float f = f_of_bf16(v[j]);
    f = lrelu((f - p2.x) * p2.y);
    o[j] = bf16_of(f);
  }
  *ptr = o;
}

extern "C" void kernel_launch(void* const* d_in, const int* in_sizes, int n_in,
                              void* d_out, int out_size, void* d_ws, size_t ws_size,
                              hipStream_t stream) {
  (void)in_sizes; (void)n_in; (void)out_size; (void)ws_size;
  const float* x       = (const float*)d_in[0];
  const float* w_q     = (const float*)d_in[1];
  const float* w_k     = (const float*)d_in[2];
  const float* w_direct= (const float*)d_in[3];
  const float* w_nl    = (const float*)d_in[4];
  const float* w_head  = (const float*)d_in[5];
  const float* w_down1 = (const float*)d_in[6];
  const float* w_down2 = (const float*)d_in[7];
  const float* w_e0    = (const float*)d_in[8];
  const float* w_up2   = (const float*)d_in[9];
  const float* w_up1   = (const float*)d_in[10];
  const float* w_tail  = (const float*)d_in[11];
  float* out = (float*)d_out;

  // ---- workspace layout (bytes), liveness-aliased ----
  char* ws = (char*)d_ws;
  float* qg = (float*)(ws + 0);
  float* kg = (float*)(ws + 13603328);
  __hip_bfloat16* qb3  = (__hip_bfloat16*)(ws + 27206656);
  __hip_bfloat16* kb2  = (__hip_bfloat16*)(ws + 34008320);
  __hip_bfloat16* dotb = (__hip_bfloat16*)(ws + 40726784);
  __hip_bfloat16* u1b  = dotb;
  __hip_bfloat16* yb   = (__hip_bfloat16*)(ws + 67600640);
  __hip_bfloat16* d0b  = (__hip_bfloat16*)(ws + 94474496);
  short* wfb           = (short*)(ws + 121348352);
  short* wmc           = (short*)(ws + 121399552);
  float2* partials     = (float2*)(ws + 121557248);
  float2* mv           = (float2*)(ws + 124834048);
  __hip_bfloat16* d1b  = (__hip_bfloat16*)(ws + 0);
  __hip_bfloat16* d2b  = (__hip_bfloat16*)(ws + 6885376);
  __hip_bfloat16* e0b  = (__hip_bfloat16*)(ws + 8691712);
  __hip_bfloat16* u2b  = (__hip_bfloat16*)(ws + 13603328);

  short* w_headb = wmc + 0;
  short* w_d1b   = wmc + 9216;
  short* w_d2b   = wmc + 25600;
  short* w_e0b   = wmc + 41984;
  short* w_u2b   = wmc + 51200;
  short* w_u1b   = wmc + 60416;

  rim4_kernel<<<dim3(16, 4, 4), 256, 0, stream>>>(qg, kg, qb3, kb2);
  halo_zero3<<<dim3(11, 4, 3), 256, 0, stream>>>(yb, d0b, dotb);
  wprep_kernel<<<dim3(72, 1, 6), 256, 0, stream>>>(
      w_head, w_down1, w_down2, w_e0, w_up2, w_up1, wmc);

  qk_kernel<<<1600, 256, 0, stream>>>(x, w_q, w_k, qg, kg, qb3, kb2);
  dot_kernel<<<1600, 256, 0, stream>>>(qg, kg, dotb);
  wfuse_kernel<<<100, 256, 0, stream>>>(w_direct, w_nl, wfb);

  // fused front conv: no-LDS, NROW=1 (6400 waves)
  fconv_kernel<<<dim3(5, 80, 4), 256, 0, stream>>>(qb3, kb2, dotb, wfb, yb);
  fixup_kernel<<<dim3(5, 4), 256, 0, stream>>>(qb3, w_direct, w_nl, yb);

  halo_zero5<<<dim3(11, 4, 5), 256, 0, stream>>>(d1b, u2b, d2b, e0b, u1b);

  // ---- bf16 MFMA conv stack (no LDS, frag-ordered weights from global) ----
  mconv<32, 3, 1, false, false, 4, 1><<<dim3(5, 80, 4), 256, 0, stream>>>(
      yb, nullptr, w_headb, d0b, partials, 320, 320, 320, 320);
  stats_kernel<<<128, 256, 0, stream>>>(partials, mv, 1600, 102400);
  bnorm_kernel<<<6400, 256, 0, stream>>>(d0b, mv, 320, 320);

  mconv<32, 4, 2, false, false, 2, 1><<<dim3(5, 40, 4), 256, 0, stream>>>(
      d0b, nullptr, w_d1b, d1b, partials, 320, 320, 160, 160);
  stats_kernel<<<128, 256, 0, stream>>>(partials, mv, 800, 25600);
  bnorm_kernel<<<1600, 256, 0, stream>>>(d1b, mv, 160, 160);

  mconv<32, 4, 2, false, false, 1, 1><<<dim3(5, 20, 4), 256, 0, stream>>>(
      d1b, nullptr, w_d2b, d2b, partials, 160, 160, 80, 80);
  stats_kernel<<<128, 256, 0, stream>>>(partials, mv, 400, 6400);
  bnorm_kernel<<<400, 256, 0, stream>>>(d2b, mv, 80, 80);

  mconv<32, 3, 1, false, false, 1, 1><<<dim3(5, 20, 4), 256, 0, stream>>>(
      d2b, nullptr, w_e0b, e0b, partials, 80, 80, 80, 80);
  stats_kernel<<<128, 256, 0, stream>>>(partials, mv, 400, 6400);
  bnorm_kernel<<<400, 256, 0, stream>>>(e0b, mv, 80, 80);

  mconv<32, 3, 1, true, false, 2, 1><<<dim3(5, 40, 4), 256, 0, stream>>>(
      e0b, nullptr, w_u2b, u2b, partials, 80, 80, 160, 160);
  stats_kernel<<<128, 256, 0, stream>>>(partials, mv, 800, 25600);
  bnorm_kernel<<<1600, 256, 0, stream>>>(u2b, mv, 160, 160);

  mconv<64, 3, 1, true, true, 4, 1><<<dim3(5, 80, 4), 256, 0, stream>>>(
      d1b, u2b, w_u1b, u1b, partials, 160, 160, 320, 320);
  stats_kernel<<<128, 256, 0, stream>>>(partials, mv, 1600, 102400);
  bnorm_kernel<<<6400, 256, 0, stream>>>(u1b, mv, 320, 320);

  tail2_kernel<<<dim3(20, 80, 4), 256, 0, stream>>>(d0b, u1b, w_tail, out);
}